// Round 4
// baseline (236.256 us; speedup 1.0000x reference)
//
#include <hip/hip_runtime.h>

// MultiScaleSampler: per-point 5->32->32->32->3 MLP + softmax(3), scattered to
// zeroed (H*W,3) fp32 output at unique yi.
// R4 = R3 with the macro-recursion bug fixed (preprocessor doesn't expand a
// macro inside itself; use two identical repetition macros RPT32/RPT32B).
// Strategy: NO arrays — 32 named scalar accumulators per layer, streaming
// schedule (produce one activation, fold into all 32 next-layer accumulators,
// discard). Peak live ~70 VGPRs. Weights are wave-uniform s_loads -> SGPR
// operands of v_fmac_f32.

#define W_IMG 2048
#define NFEAT 32

#define RPT32(F) F(0) F(1) F(2) F(3) F(4) F(5) F(6) F(7) \
                 F(8) F(9) F(10) F(11) F(12) F(13) F(14) F(15) \
                 F(16) F(17) F(18) F(19) F(20) F(21) F(22) F(23) \
                 F(24) F(25) F(26) F(27) F(28) F(29) F(30) F(31)

// second copy for nesting (a macro cannot expand recursively inside itself)
#define RPT32B(F) F(0) F(1) F(2) F(3) F(4) F(5) F(6) F(7) \
                  F(8) F(9) F(10) F(11) F(12) F(13) F(14) F(15) \
                  F(16) F(17) F(18) F(19) F(20) F(21) F(22) F(23) \
                  F(24) F(25) F(26) F(27) F(28) F(29) F(30) F(31)

__global__ __launch_bounds__(256) void fill_zero(float* __restrict__ out, int n) {
    int n4 = n >> 2;
    float4* o4 = (float4*)out;
    int stride = gridDim.x * blockDim.x;
    for (int i = blockIdx.x * blockDim.x + threadIdx.x; i < n4; i += stride)
        o4[i] = make_float4(0.f, 0.f, 0.f, 0.f);
    int t = (n4 << 2) + (blockIdx.x * blockDim.x + threadIdx.x);
    if (t < n) out[t] = 0.f;
}

__global__ __launch_bounds__(256, 4) void msampler_mlp(
    const float* __restrict__ grid,   // (2, N): x row then y row
    const int*   __restrict__ yi,     // (N,)
    const float* __restrict__ m,      // (3,3)
    const float* __restrict__ W1, const float* __restrict__ b1,   // (5,32),(32)
    const float* __restrict__ W2, const float* __restrict__ b2,   // (32,32),(32)
    const float* __restrict__ W3, const float* __restrict__ b3,   // (32,32),(32)
    const float* __restrict__ W4, const float* __restrict__ b4,   // (32,3),(3)
    float* __restrict__ out, int N)
{
    int i = blockIdx.x * blockDim.x + threadIdx.x;
    if (i >= N) return;

    float gx = grid[i];
    float gy = grid[N + i];
    int   y  = yi[i];
    int   py = y >> 11;            // / 2048
    int   px = y & (W_IMG - 1);    // % 2048

    // uniform homography math (SGPR)
    float m00=m[0], m01=m[1], m02=m[2];
    float m10=m[3], m11=m[4], m12=m[5];
    float m20=m[6], m21=m[7], m22=m[8];
    float det = m00*(m11*m22 - m12*m21)
              - m01*(m10*m22 - m12*m20)
              + m02*(m10*m21 - m11*m20);
    float denom = m20*(float)px + m21*(float)py + m22;
    float ad   = fabsf(denom);
    float dsda = fabsf(det) / (ad*ad*ad);

    float fx = gx - floorf(gx);
    float fy = gy - floorf(gy);
    float x0 = fx, x1 = fy, x2 = 1.f - fx, x3 = 1.f - fy, x4 = dsda;

    // ---- layer-2 accumulators, init with bias ----
#define DECL_C(t) float c##t = b2[t];
    RPT32(DECL_C)
#undef DECL_C

    // ---- layer 1 (5->32) streamed into layer-2 accumulation ----
    // for each layer-1 output j: a = relu(b1[j] + x·W1[:,j]); c_t += a*W2[j][t]
#define FOLD_C(t) c##t = fmaf(a, W2j[t], c##t);
#define L1STEP(j) { \
        float a = b1[j]; \
        a = fmaf(x0, W1[0*NFEAT + j], a); \
        a = fmaf(x1, W1[1*NFEAT + j], a); \
        a = fmaf(x2, W1[2*NFEAT + j], a); \
        a = fmaf(x3, W1[3*NFEAT + j], a); \
        a = fmaf(x4, W1[4*NFEAT + j], a); \
        a = fmaxf(a, 0.f); \
        const float* __restrict__ W2j = W2 + (j)*NFEAT; \
        RPT32B(FOLD_C) }
    RPT32(L1STEP)
#undef L1STEP
#undef FOLD_C

    // ---- layer-3 accumulators ----
#define DECL_D(t) float d##t = b3[t];
    RPT32(DECL_D)
#undef DECL_D

    // ---- layer 2 outputs streamed into layer-3 accumulation ----
#define FOLD_D(t) d##t = fmaf(rc, W3k[t], d##t);
#define L3STEP(k) { \
        float rc = fmaxf(c##k, 0.f); \
        const float* __restrict__ W3k = W3 + (k)*NFEAT; \
        RPT32B(FOLD_D) }
    RPT32(L3STEP)
#undef L3STEP
#undef FOLD_D

    // ---- layer 4 (32->3) streamed ----
    float l0 = b4[0], l1 = b4[1], l2 = b4[2];
#define L4STEP(t) { \
        float rd = fmaxf(d##t, 0.f); \
        l0 = fmaf(rd, W4[(t)*3 + 0], l0); \
        l1 = fmaf(rd, W4[(t)*3 + 1], l1); \
        l2 = fmaf(rd, W4[(t)*3 + 2], l2); }
    RPT32(L4STEP)
#undef L4STEP

    // softmax(3)
    float mx = fmaxf(l0, fmaxf(l1, l2));
    float e0 = __expf(l0 - mx), e1 = __expf(l1 - mx), e2 = __expf(l2 - mx);
    float inv = 1.f / (e0 + e1 + e2);

    int o = y * 3;
    out[o + 0] = e0 * inv;
    out[o + 1] = e1 * inv;
    out[o + 2] = e2 * inv;
}

extern "C" void kernel_launch(void* const* d_in, const int* in_sizes, int n_in,
                              void* d_out, int out_size, void* d_ws, size_t ws_size,
                              hipStream_t stream) {
    const float* grid = (const float*)d_in[0];
    const int*   yi   = (const int*)  d_in[1];
    const float* m    = (const float*)d_in[2];
    const float* W1   = (const float*)d_in[3];
    const float* b1   = (const float*)d_in[4];
    const float* W2   = (const float*)d_in[5];
    const float* b2   = (const float*)d_in[6];
    const float* W3   = (const float*)d_in[7];
    const float* b3   = (const float*)d_in[8];
    const float* W4   = (const float*)d_in[9];
    const float* b4   = (const float*)d_in[10];
    float* out = (float*)d_out;

    int N = in_sizes[1];  // yi element count

    fill_zero<<<1024, 256, 0, stream>>>(out, out_size);

    int block = 256;
    int grid_sz = (N + block - 1) / block;
    msampler_mlp<<<grid_sz, block, 0, stream>>>(
        grid, yi, m, W1, b1, W2, b2, W3, b3, W4, b4, out, N);
}

// Round 5
// 130.539 us; speedup vs baseline: 1.8098x; 1.8098x over previous
//
#include <hip/hip_runtime.h>

// MultiScaleSampler R5: all four MLP layers on the MFMA pipe (f16 in, f32 acc),
// computed in TRANSPOSED orientation D[out][pt] = W^T * h^T so that:
//   - activation B-fragments are contiguous ds_read_b128 from [pt][feat] LDS
//   - C-fragment outputs (4 consecutive outs, fixed pt) pack into ds_write_b64
// Weights live as per-lane A-fragments in VGPRs (loaded once) — this removes
// the 2300-value wave-uniform s_load storm that defeated the allocator in
// R1-R4 (VGPR=36 + AGPR shuffling). Per-wave-private LDS slices; 4 barriers.

#define W_IMG 2048
#define NF    32
#define PST   80            // LDS bytes per point-row: 32 f16 (64 B) + 16 B pad
#define BUF   (64 * PST)    // 5120 B per buffer per wave

typedef __attribute__((ext_vector_type(8))) _Float16 f16x8;
typedef __attribute__((ext_vector_type(4))) _Float16 f16x4;
typedef __attribute__((ext_vector_type(4))) float    f32x4;

__global__ __launch_bounds__(256) void fill_zero(float* __restrict__ out, int n) {
    int n4 = n >> 2;
    float4* o4 = (float4*)out;
    int stride = gridDim.x * blockDim.x;
    for (int i = blockIdx.x * blockDim.x + threadIdx.x; i < n4; i += stride)
        o4[i] = make_float4(0.f, 0.f, 0.f, 0.f);
    int t = (n4 << 2) + (blockIdx.x * blockDim.x + threadIdx.x);
    if (t < n) out[t] = 0.f;
}

__global__ __launch_bounds__(256, 4) void msampler_mlp(
    const float* __restrict__ grid,   // (2, N)
    const int*   __restrict__ yi,     // (N,)
    const float* __restrict__ m,      // (3,3)
    const float* __restrict__ W1, const float* __restrict__ b1,   // (5,32),(32)
    const float* __restrict__ W2, const float* __restrict__ b2,   // (32,32),(32)
    const float* __restrict__ W3, const float* __restrict__ b3,   // (32,32),(32)
    const float* __restrict__ W4, const float* __restrict__ b4,   // (32,3),(3)
    float* __restrict__ out, int N)
{
    const int tid  = threadIdx.x;
    const int lane = tid & 63;
    const int wave = tid >> 6;
    const int lm   = lane & 15;   // MFMA m/n index within tile
    const int lq   = lane >> 4;   // MFMA k-quad
    const int i    = blockIdx.x * 256 + tid;
    const int ic   = i < N ? i : N - 1;

    __shared__ __align__(16) char smem[4 * 2 * BUF];
    char* bufA = smem + wave * (2 * BUF);
    char* bufB = bufA + BUF;

    // ---- one-time per-lane weight fragments (A = W^T: A[m=out][k=in]) ----
    f16x8 a1[2], a2[2], a3[2];
    f32x4 cb1[2], cb2[2], cb3[2];
#pragma unroll
    for (int mh = 0; mh < 2; ++mh) {
        int outc = 16 * mh + lm;
#pragma unroll
        for (int j = 0; j < 8; ++j) {
            int k = lq * 8 + j;
            a1[mh][j] = (k < 5) ? (_Float16)W1[k * NF + outc] : (_Float16)0.0f;
            a2[mh][j] = (_Float16)W2[k * NF + outc];
            a3[mh][j] = (_Float16)W3[k * NF + outc];
        }
#pragma unroll
        for (int r = 0; r < 4; ++r) {
            int o = 16 * mh + lq * 4 + r;   // C row = out index
            cb1[mh][r] = b1[o];
            cb2[mh][r] = b2[o];
            cb3[mh][r] = b3[o];
        }
    }

    // ---- per-point features ----
    float gx = grid[ic];
    float gy = grid[N + ic];
    int   y  = yi[ic];
    int   py = y >> 11;            // / 2048
    int   px = y & (W_IMG - 1);    // % 2048

    float m00=m[0], m01=m[1], m02=m[2];
    float m10=m[3], m11=m[4], m12=m[5];
    float m20=m[6], m21=m[7], m22=m[8];
    float det = m00*(m11*m22 - m12*m21)
              - m01*(m10*m22 - m12*m20)
              + m02*(m10*m21 - m11*m20);
    float denom = m20*(float)px + m21*(float)py + m22;
    float ad    = fabsf(denom);
    float dsda  = fabsf(det) / (ad*ad*ad);
    dsda = fminf(dsda, 60000.f);   // f16-range clamp; softmax saturated long before

    float fx = gx - floorf(gx);
    float fy = gy - floorf(gy);

    // write features (k=0..4, zero-pad to 32) into bufA row [pt=lane]
    {
        f16x8 f0;
        f0[0] = (_Float16)fx;        f0[1] = (_Float16)fy;
        f0[2] = (_Float16)(1.f-fx);  f0[3] = (_Float16)(1.f-fy);
        f0[4] = (_Float16)dsda;      f0[5] = (_Float16)0.0f;
        f0[6] = (_Float16)0.0f;      f0[7] = (_Float16)0.0f;
        f16x8 z = f0 - f0;           // zeros
        char* row = bufA + lane * PST;
        *(f16x8*)(row)      = f0;
        *(f16x8*)(row + 16) = z;
        *(f16x8*)(row + 32) = z;
        *(f16x8*)(row + 48) = z;
    }
    __syncthreads();

    // ---- MFMA layer: read B-frags (h^T) from SRC, D = A*B + bias, relu,
    //      packed b64 write to DST in [pt][feat] ----
#define MFMA_LAYER(SRC, DST, AF, CB)                                          \
    {                                                                         \
        f16x8 bf[4];                                                          \
        _Pragma("unroll")                                                     \
        for (int g = 0; g < 4; ++g)                                           \
            bf[g] = *(const f16x8*)((SRC) + (16*g + lm) * PST + lq * 16);     \
        _Pragma("unroll")                                                     \
        for (int mh = 0; mh < 2; ++mh) {                                      \
            _Pragma("unroll")                                                 \
            for (int g = 0; g < 4; ++g) {                                     \
                f32x4 d = __builtin_amdgcn_mfma_f32_16x16x32_f16(             \
                    AF[mh], bf[g], CB[mh], 0, 0, 0);                          \
                f16x4 o;                                                      \
                _Pragma("unroll")                                             \
                for (int r = 0; r < 4; ++r)                                   \
                    o[r] = (_Float16)fminf(fmaxf(d[r], 0.f), 60000.f);        \
                *(f16x4*)((DST) + (16*g + lm) * PST + (16*mh + lq*4) * 2) = o;\
            }                                                                 \
        }                                                                     \
    }

    MFMA_LAYER(bufA, bufB, a1, cb1)   // layer 1: feats -> h1
    __syncthreads();
    MFMA_LAYER(bufB, bufA, a2, cb2)   // layer 2: h1 -> h2
    __syncthreads();
    MFMA_LAYER(bufA, bufB, a3, cb3)   // layer 3: h2 -> h3
    __syncthreads();
#undef MFMA_LAYER

    // ---- layer 4 (32->3) in fp32 VALU + softmax + scatter ----
    float l0 = b4[0], l1 = b4[1], l2 = b4[2];
    {
        const char* row = bufB + lane * PST;
#pragma unroll
        for (int c = 0; c < 4; ++c) {
            f16x8 hv = *(const f16x8*)(row + c * 16);
#pragma unroll
            for (int j = 0; j < 8; ++j) {
                float h = (float)hv[j];
                int k = c * 8 + j;
                l0 = fmaf(h, W4[k*3 + 0], l0);
                l1 = fmaf(h, W4[k*3 + 1], l1);
                l2 = fmaf(h, W4[k*3 + 2], l2);
            }
        }
    }
    float mx = fmaxf(l0, fmaxf(l1, l2));
    float e0 = __expf(l0 - mx), e1 = __expf(l1 - mx), e2 = __expf(l2 - mx);
    float inv = 1.f / (e0 + e1 + e2);

    if (i < N) {
        int o = y * 3;
        out[o + 0] = e0 * inv;
        out[o + 1] = e1 * inv;
        out[o + 2] = e2 * inv;
    }
}

extern "C" void kernel_launch(void* const* d_in, const int* in_sizes, int n_in,
                              void* d_out, int out_size, void* d_ws, size_t ws_size,
                              hipStream_t stream) {
    const float* grid = (const float*)d_in[0];
    const int*   yi   = (const int*)  d_in[1];
    const float* m    = (const float*)d_in[2];
    const float* W1   = (const float*)d_in[3];
    const float* b1   = (const float*)d_in[4];
    const float* W2   = (const float*)d_in[5];
    const float* b2   = (const float*)d_in[6];
    const float* W3   = (const float*)d_in[7];
    const float* b3   = (const float*)d_in[8];
    const float* W4   = (const float*)d_in[9];
    const float* b4   = (const float*)d_in[10];
    float* out = (float*)d_out;

    int N = in_sizes[1];  // yi element count

    fill_zero<<<1024, 256, 0, stream>>>(out, out_size);

    int block = 256;
    int grid_sz = (N + block - 1) / block;
    msampler_mlp<<<grid_sz, block, 0, stream>>>(
        grid, yi, m, W1, b1, W2, b2, W3, b3, W4, b4, out, N);
}

// Round 7
// 129.525 us; speedup vs baseline: 1.8240x; 1.0078x over previous
//
#include <hip/hip_runtime.h>

// MultiScaleSampler R7 = R6 with the cvt_pkrtz type clash fixed (plain
// (_Float16) casts; compiler packs the halves itself).
// Structure: 4-layer MLP entirely on MFMA (f16 in, f32 acc), transposed
// orientation D[out][pt]; wave-private LDS, NO barriers; LDS in B-fragment
// order (consumer reads lane*16 b128 conflict-free, producer writes 8B
// halves <=2-way = free); 2 points/lane; layer 4 as 9th MFMA per tile-group.

#define W_IMG 2048
#define NF    32

typedef __attribute__((ext_vector_type(8))) _Float16 f16x8;
typedef __attribute__((ext_vector_type(4))) _Float16 f16x4;
typedef __attribute__((ext_vector_type(4))) float    f32x4;

__global__ __launch_bounds__(256) void fill_zero(float* __restrict__ out, int n) {
    int n4 = n >> 2;
    float4* o4 = (float4*)out;
    int stride = gridDim.x * blockDim.x;
    for (int i = blockIdx.x * blockDim.x + threadIdx.x; i < n4; i += stride)
        o4[i] = make_float4(0.f, 0.f, 0.f, 0.f);
    int t = (n4 << 2) + (blockIdx.x * blockDim.x + threadIdx.x);
    if (t < n) out[t] = 0.f;
}

__global__ __launch_bounds__(256, 4) void msampler_mlp(
    const float* __restrict__ grid,   // (2, N)
    const int*   __restrict__ yi,     // (N,)
    const float* __restrict__ m,      // (3,3)
    const float* __restrict__ W1, const float* __restrict__ b1,   // (5,32),(32)
    const float* __restrict__ W2, const float* __restrict__ b2,   // (32,32),(32)
    const float* __restrict__ W3, const float* __restrict__ b3,   // (32,32),(32)
    const float* __restrict__ W4, const float* __restrict__ b4,   // (32,3),(3)
    float* __restrict__ out, int N)
{
    const int tid  = threadIdx.x;
    const int lane = tid & 63;
    const int wave = tid >> 6;
    const int lm   = lane & 15;
    const int lq   = lane >> 4;

    __shared__ __align__(16) char smem[4 * 8192];
    char* buf = smem + wave * 8192;   // 8 tiles x 1024B, wave-private

    // ---- one-time weight fragments (A = W^T: A[m=out][k=in]) ----
    f16x8 a1[2], a2[2], a3[2], a4;
    f32x4 cb1[2], cb2[2], cb3[2], cb4;
#pragma unroll
    for (int mh = 0; mh < 2; ++mh) {
        int outc = 16 * mh + lm;
#pragma unroll
        for (int j = 0; j < 8; ++j) {
            int k = lq * 8 + j;
            a1[mh][j] = (k < 5) ? (_Float16)W1[k * NF + outc] : (_Float16)0.0f;
            a2[mh][j] = (_Float16)W2[k * NF + outc];
            a3[mh][j] = (_Float16)W3[k * NF + outc];
        }
#pragma unroll
        for (int r = 0; r < 4; ++r) {
            int o = 16 * mh + lq * 4 + r;
            cb1[mh][r] = b1[o];
            cb2[mh][r] = b2[o];
            cb3[mh][r] = b3[o];
        }
    }
#pragma unroll
    for (int j = 0; j < 8; ++j) {
        int k = lq * 8 + j;
        a4[j] = (lm < 3) ? (_Float16)W4[k * 3 + lm] : (_Float16)0.0f;
    }
#pragma unroll
    for (int r = 0; r < 4; ++r) {
        int o = lq * 4 + r;
        cb4[r] = (o < 3) ? b4[o] : 0.f;
    }

    // ---- uniform homography scalars ----
    float m00=m[0], m01=m[1], m02=m[2];
    float m10=m[3], m11=m[4], m12=m[5];
    float m20=m[6], m21=m[7], m22=m[8];
    float det = m00*(m11*m22 - m12*m21)
              - m01*(m10*m22 - m12*m20)
              + m02*(m10*m21 - m11*m20);
    float adet = fabsf(det);

    // ---- features for 2 points (slots s = t*64 + lane), write B-frag slot ----
    const int i0 = blockIdx.x * 512 + wave * 128;
    int ya[2];
#pragma unroll
    for (int t = 0; t < 2; ++t) {
        int i  = i0 + t * 64 + lane;
        int ic = i < N ? i : N - 1;
        float gx = grid[ic];
        float gy = grid[N + ic];
        int   y  = yi[ic];
        ya[t] = y;
        int py = y >> 11;            // / 2048
        int px = y & (W_IMG - 1);    // % 2048
        float denom = m20*(float)px + m21*(float)py + m22;
        float ad    = fabsf(denom);
        float dsda  = fminf(adet / (ad*ad*ad), 60000.f);  // f16-range clamp
        float fx = gx - floorf(gx);
        float fy = gy - floorf(gy);
        f16x8 f;
        f[0] = (_Float16)fx;         f[1] = (_Float16)fy;
        f[2] = (_Float16)(1.f-fx);   f[3] = (_Float16)(1.f-fy);
        f[4] = (_Float16)dsda;       f[5] = (_Float16)0.0f;
        f[6] = (_Float16)0.0f;       f[7] = (_Float16)0.0f;
        int g = t * 4 + lq;          // tile of this point
        *(f16x8*)(buf + g * 1024 + lm * 16) = f;   // consumer slot (lq_c=0, lm)
    }
    // zero k=8..31 regions of all 8 tiles (48 chunks x 16B per tile);
    // lane covers tile lane>>3, chunks (lane&7)+8j
    {
        f16x8 z = {};
#pragma unroll
        for (int j = 0; j < 6; ++j) {
            int T  = lane >> 3;
            int ch = (lane & 7) + 8 * j;
            *(f16x8*)(buf + T * 1024 + 256 + ch * 16) = z;
        }
    }

    // write offset for D-frag (mh, tile T): consumer lane (2mh + lq/2, lm),
    // half (lq&1)
    const int woff = ((lq >> 1) * 16 + lm) * 16 + (lq & 1) * 8;

    // ---- layers 1..3: read B-frags, MFMA, relu+clamp+cvt, write frags ----
#define LAYER(AF, CB)                                                          \
    _Pragma("unroll")                                                          \
    for (int tg = 0; tg < 2; ++tg) {                                           \
        f16x8 bf[4];                                                           \
        _Pragma("unroll")                                                      \
        for (int q = 0; q < 4; ++q)                                            \
            bf[q] = *(const f16x8*)(buf + (tg*4 + q) * 1024 + lane * 16);      \
        _Pragma("unroll")                                                      \
        for (int q = 0; q < 4; ++q) {                                          \
            int T = tg * 4 + q;                                                \
            _Pragma("unroll")                                                  \
            for (int mh = 0; mh < 2; ++mh) {                                   \
                f32x4 d = __builtin_amdgcn_mfma_f32_16x16x32_f16(              \
                    AF[mh], bf[q], CB[mh], 0, 0, 0);                           \
                f16x4 o;                                                       \
                _Pragma("unroll")                                              \
                for (int r = 0; r < 4; ++r)                                    \
                    o[r] = (_Float16)fminf(fmaxf(d[r], 0.f), 60000.f);         \
                *(f16x4*)(buf + T * 1024 + mh * 512 + woff) = o;               \
            }                                                                  \
        }                                                                      \
    }

    LAYER(a1, cb1)
    LAYER(a2, cb2)
    LAYER(a3, cb3)
#undef LAYER

    // ---- layer 4: one MFMA per tile; logits (rows 0..2) sit in lq==0 lanes;
    //      stash to pt-indexed slots (first 2KB, tiles already consumed) ----
#pragma unroll
    for (int tg = 0; tg < 2; ++tg) {
        f16x8 bf[4];
#pragma unroll
        for (int q = 0; q < 4; ++q)
            bf[q] = *(const f16x8*)(buf + (tg*4 + q) * 1024 + lane * 16);
#pragma unroll
        for (int q = 0; q < 4; ++q) {
            int T = tg * 4 + q;
            f32x4 d = __builtin_amdgcn_mfma_f32_16x16x32_f16(a4, bf[q], cb4, 0, 0, 0);
            if (lq == 0)
                *(f32x4*)(buf + (T * 16 + lm) * 16) = d;   // pt slot, 16B
        }
    }

    // ---- softmax + scatter for own 2 points ----
#pragma unroll
    for (int t = 0; t < 2; ++t) {
        int s = t * 64 + lane;
        f32x4 L = *(const f32x4*)(buf + s * 16);
        float l0 = L[0], l1 = L[1], l2 = L[2];
        float mx = fmaxf(l0, fmaxf(l1, l2));
        float e0 = __expf(l0 - mx), e1 = __expf(l1 - mx), e2 = __expf(l2 - mx);
        float inv = 1.f / (e0 + e1 + e2);
        int i = i0 + s;
        if (i < N) {
            int o = ya[t] * 3;
            out[o + 0] = e0 * inv;
            out[o + 1] = e1 * inv;
            out[o + 2] = e2 * inv;
        }
    }
}

extern "C" void kernel_launch(void* const* d_in, const int* in_sizes, int n_in,
                              void* d_out, int out_size, void* d_ws, size_t ws_size,
                              hipStream_t stream) {
    const float* grid = (const float*)d_in[0];
    const int*   yi   = (const int*)  d_in[1];
    const float* m    = (const float*)d_in[2];
    const float* W1   = (const float*)d_in[3];
    const float* b1   = (const float*)d_in[4];
    const float* W2   = (const float*)d_in[5];
    const float* b2   = (const float*)d_in[6];
    const float* W3   = (const float*)d_in[7];
    const float* b3   = (const float*)d_in[8];
    const float* W4   = (const float*)d_in[9];
    const float* b4   = (const float*)d_in[10];
    float* out = (float*)d_out;

    int N = in_sizes[1];  // yi element count

    fill_zero<<<1024, 256, 0, stream>>>(out, out_size);

    int grid_sz = (N + 511) / 512;   // 512 points per block (4 waves x 128)
    msampler_mlp<<<grid_sz, 256, 0, stream>>>(
        grid, yi, m, W1, b1, W2, b2, W3, b3, W4, b4, out, N);
}